// Round 1
// baseline (212.297 us; speedup 1.0000x reference)
//
#include <hip/hip_runtime.h>
#include <math.h>

#define N_PTS 1024
#define HID   256
#define FEAT  2048

// ---------------- split-K GEMM: C += A@B (atomic accumulate) ----------------
// BM=64 BN=64 BK=16, 256 threads, 4x4 micro-tile per thread.
__global__ __launch_bounds__(256) void gemm_splitk(
    const float* __restrict__ A, const float* __restrict__ B,
    float* __restrict__ C, int M, int N, int K, int kchunk)
{
    __shared__ float As[16][68];   // [k][m], padded
    __shared__ float Bs[16][64];   // [k][n]
    const int tid = threadIdx.x;
    const int tx = tid & 15;       // micro col group
    const int ty = tid >> 4;       // micro row group
    const int mBase = blockIdx.y * 64;
    const int nBase = blockIdx.x * 64;
    const int kBeg = blockIdx.z * kchunk;
    const int kEnd = kBeg + kchunk;

    const int lm  = tid >> 2;      // 0..63 A-row
    const int lkq = tid & 3;       // 0..3  A k-quad
    const int lk  = tid >> 4;      // 0..15 B-row (k)
    const int lnq = tid & 15;      // 0..15 B n-quad

    float acc[4][4];
    #pragma unroll
    for (int r = 0; r < 4; r++)
        #pragma unroll
        for (int c = 0; c < 4; c++) acc[r][c] = 0.f;

    for (int kt = kBeg; kt < kEnd; kt += 16) {
        float4 av = *(const float4*)&A[(size_t)(mBase + lm) * K + kt + lkq * 4];
        float4 bv = *(const float4*)&B[(size_t)(kt + lk) * N + nBase + lnq * 4];
        As[lkq*4+0][lm] = av.x;
        As[lkq*4+1][lm] = av.y;
        As[lkq*4+2][lm] = av.z;
        As[lkq*4+3][lm] = av.w;
        *(float4*)&Bs[lk][lnq*4] = bv;
        __syncthreads();
        #pragma unroll
        for (int k = 0; k < 16; k++) {
            float4 a = *(const float4*)&As[k][ty*4];
            float4 b = *(const float4*)&Bs[k][tx*4];
            float ar[4] = {a.x, a.y, a.z, a.w};
            float br[4] = {b.x, b.y, b.z, b.w};
            #pragma unroll
            for (int r = 0; r < 4; r++)
                #pragma unroll
                for (int c = 0; c < 4; c++)
                    acc[r][c] = fmaf(ar[r], br[c], acc[r][c]);
        }
        __syncthreads();
    }
    #pragma unroll
    for (int r = 0; r < 4; r++)
        #pragma unroll
        for (int c = 0; c < 4; c++)
            unsafeAtomicAdd(&C[(size_t)(mBase + ty*4 + r) * N + nBase + tx*4 + c],
                            acc[r][c]);
}

// ---------------- per-column sum / sumsq (atomic partials) ----------------
__global__ __launch_bounds__(256) void colstats(
    const float* __restrict__ X, float* __restrict__ sum,
    float* __restrict__ sq, int rowsPerBlock)
{
    const int c = threadIdx.x;            // column 0..255
    const int r0 = blockIdx.x * rowsPerBlock;
    float s = 0.f, q = 0.f;
    for (int r = r0; r < r0 + rowsPerBlock; ++r) {
        float v = X[r * HID + c];
        s += v;
        q = fmaf(v, v, q);
    }
    unsafeAtomicAdd(&sum[c], s);
    unsafeAtomicAdd(&sq[c], q);
}

// ---------------- BN (train-mode, biased var) + ReLU ----------------
__global__ __launch_bounds__(256) void bn_relu(
    const float* __restrict__ X, const float* __restrict__ sum,
    const float* __restrict__ sq, const float* __restrict__ g,
    const float* __restrict__ bt, float* __restrict__ Y)
{
    const int idx = blockIdx.x * 256 + threadIdx.x;  // float4 index, 65536 total
    const int cq = (idx & 63) * 4;
    float4 x = ((const float4*)X)[idx];
    float xv[4] = {x.x, x.y, x.z, x.w};
    float o[4];
    #pragma unroll
    for (int e = 0; e < 4; e++) {
        const int c = cq + e;
        float m   = sum[c] * (1.f / 1024.f);
        float var = fmaf(-m, m, sq[c] * (1.f / 1024.f));
        float rstd = rsqrtf(var + 1e-5f);
        o[e] = fmaxf(fmaf(g[c] * rstd, xv[e] - m, bt[c]), 0.f);
    }
    ((float4*)Y)[idx] = make_float4(o[0], o[1], o[2], o[3]);
}

// ---------------- fused all-pairs edge network + node update ----------------
// Block i: enumerate j with labels[j]==labels[i], j!=i via per-wave ballot;
// for each match: logit = sum_k relu(hi[i,k]+hj[j,k]+bwe1[k])*We2[k] + bwe2,
// w = sigmoid(logit); acc += w*di[j]; wsum += w. out = di[i] + acc/wsum.
__global__ __launch_bounds__(256) void pair_update(
    const float* __restrict__ di, const float* __restrict__ hi,
    const float* __restrict__ hj, const float* __restrict__ bwe1,
    const float* __restrict__ We2, const float* __restrict__ bwe2,
    const int* __restrict__ labels, float* __restrict__ out)
{
    __shared__ int   slab[N_PTS];
    __shared__ float sacc[4][HID];
    __shared__ float swsum[4];
    const int i = blockIdx.x;
    const int tid = threadIdx.x;
    const int lane = tid & 63;
    const int wave = tid >> 6;

    for (int t = tid; t < N_PTS; t += 256) slab[t] = labels[t];
    __syncthreads();

    const int myLab = slab[i];
    // lane covers k = 4*lane .. 4*lane+3 (identical mapping in all 4 waves)
    float4 hv_i = ((const float4*)(hi + (size_t)i * HID))[lane];
    float4 bw   = ((const float4*)bwe1)[lane];
    float4 w2   = ((const float4*)We2)[lane];
    const float hb0 = hv_i.x + bw.x, hb1 = hv_i.y + bw.y;
    const float hb2 = hv_i.z + bw.z, hb3 = hv_i.w + bw.w;
    const float b2 = bwe2[0];

    float a0 = 0.f, a1 = 0.f, a2 = 0.f, a3 = 0.f, wsum = 0.f;

    for (int chunk = wave * 64; chunk < N_PTS; chunk += 256) {
        const int j = chunk + lane;
        const bool match = (slab[j] == myLab) && (j != i);
        unsigned long long mask = __ballot(match);
        while (mask) {
            const int bpos = __builtin_ctzll(mask);
            mask &= mask - 1;
            const int jj = chunk + bpos;
            float4 hv = ((const float4*)(hj + (size_t)jj * HID))[lane];
            float p = fmaxf(hb0 + hv.x, 0.f) * w2.x
                    + fmaxf(hb1 + hv.y, 0.f) * w2.y
                    + fmaxf(hb2 + hv.z, 0.f) * w2.z
                    + fmaxf(hb3 + hv.w, 0.f) * w2.w;
            #pragma unroll
            for (int off = 1; off < 64; off <<= 1) p += __shfl_xor(p, off, 64);
            const float w = 1.f / (1.f + expf(-(p + b2)));
            float4 dv = ((const float4*)(di + (size_t)jj * HID))[lane];
            a0 = fmaf(w, dv.x, a0);
            a1 = fmaf(w, dv.y, a1);
            a2 = fmaf(w, dv.z, a2);
            a3 = fmaf(w, dv.w, a3);
            wsum += w;
        }
    }
    ((float4*)sacc[wave])[lane] = make_float4(a0, a1, a2, a3);
    if (lane == 0) swsum[wave] = wsum;
    __syncthreads();

    const float at = sacc[0][tid] + sacc[1][tid] + sacc[2][tid] + sacc[3][tid];
    const float wt = swsum[0] + swsum[1] + swsum[2] + swsum[3];
    const float dval = di[(size_t)i * HID + tid];
    out[(size_t)i * HID + tid] = dval + (wt > 0.f ? at / wt : 0.f);
}

extern "C" void kernel_launch(void* const* d_in, const int* in_sizes, int n_in,
                              void* d_out, int out_size, void* d_ws, size_t ws_size,
                              hipStream_t stream)
{
    const float* features = (const float*)d_in[0];
    const int*   labels   = (const int*)d_in[1];
    const float* W1   = (const float*)d_in[2];
    // d_in[3] = b1: cancels exactly through train-mode BN (mean-subtracted)
    const float* g1   = (const float*)d_in[4];
    const float* bt1  = (const float*)d_in[5];
    const float* W2   = (const float*)d_in[6];
    // d_in[7] = b2: cancels through BN
    const float* g2   = (const float*)d_in[8];
    const float* bt2  = (const float*)d_in[9];
    const float* We1  = (const float*)d_in[10];
    const float* bwe1 = (const float*)d_in[11];
    const float* We2  = (const float*)d_in[12];
    const float* bwe2 = (const float*)d_in[13];
    float* out = (float*)d_out;

    float* ws    = (float*)d_ws;
    float* x1    = ws;                 // 262144
    float* x2    = ws + 262144;        // 262144
    float* hi    = ws + 524288;        // 262144
    float* hj    = ws + 786432;        // 262144
    float* stats = ws + 1048576;       // 1024 (sum1, sq1, sum2, sq2)
    float* h     = ws + 1049600;       // 262144
    float* di    = ws + 1311744;       // 262144

    // zero atomic-accumulated buffers (x1, x2, hi, hj, stats)
    hipMemsetAsync(d_ws, 0, 1049600 * sizeof(float), stream);

    dim3 blk(256);
    // layer 1: x1 = features @ W1   (b1 folded away by BN)
    gemm_splitk<<<dim3(4, 16, 4), blk, 0, stream>>>(features, W1, x1,
                                                    N_PTS, HID, FEAT, 512);
    colstats<<<64, blk, 0, stream>>>(x1, stats, stats + 256, 16);
    bn_relu<<<256, blk, 0, stream>>>(x1, stats, stats + 256, g1, bt1, h);
    // layer 2: x2 = h @ W2
    gemm_splitk<<<dim3(4, 16, 4), blk, 0, stream>>>(h, W2, x2,
                                                    N_PTS, HID, HID, 64);
    colstats<<<64, blk, 0, stream>>>(x2, stats + 512, stats + 768, 16);
    bn_relu<<<256, blk, 0, stream>>>(x2, stats + 512, stats + 768, g2, bt2, di);
    // edge net input halves: hi = di @ We1[:H], hj = di @ We1[H:]
    gemm_splitk<<<dim3(4, 16, 4), blk, 0, stream>>>(di, We1, hi,
                                                    N_PTS, HID, HID, 64);
    gemm_splitk<<<dim3(4, 16, 4), blk, 0, stream>>>(di, We1 + HID * HID, hj,
                                                    N_PTS, HID, HID, 64);
    // fused all-pairs edge weights + node feature update
    pair_update<<<N_PTS, blk, 0, stream>>>(di, hi, hj, bwe1, We2, bwe2,
                                           labels, out);
}

// Round 3
// 162.080 us; speedup vs baseline: 1.3098x; 1.3098x over previous
//
#include <hip/hip_runtime.h>
#include <math.h>

#define N_PTS 1024
#define HID   256
#define FEAT  2048

typedef short bf16x8 __attribute__((ext_vector_type(8)));
typedef float f32x4  __attribute__((ext_vector_type(4)));

__device__ inline ushort f2bf(float f) {
    union { float f; unsigned u; } v; v.f = f;
    unsigned r = v.u + 0x7fff + ((v.u >> 16) & 1);   // round-to-nearest-even
    return (ushort)(r >> 16);
}

// ---------------- bf16 MFMA GEMM: C += A@B (atomic fp32 epilogue) ----------
// A fp32 [M][lda] row-major, B fp32 [K][ldb] row-major, C fp32 [.][ldc].
// 64x64 tile, BK=64, 256 threads (4 waves in 2x2), split-K over blockIdx.z.
// fp32->bf16 convert + B transpose happen during LDS staging.
__global__ __launch_bounds__(256) void gemm_mfma(
    const float* __restrict__ A, const float* __restrict__ B,
    float* __restrict__ C, int lda, int ldb, int ldc, int kchunk)
{
    __shared__ ushort As[64 * 72];   // [m][k], stride 72 (144B = 9*16, aligned)
    __shared__ ushort Bs[64 * 72];   // [n][k] (transposed during staging)
    const int tid  = threadIdx.x;
    const int lane = tid & 63;
    const int wave = tid >> 6;
    const int wy = wave >> 1, wx = wave & 1;   // 2x2 waves -> 32x32 each
    const int quad = lane >> 4, l16 = lane & 15;
    const int mBase = blockIdx.y * 64;
    const int nBase = blockIdx.x * 64;
    const int kBeg  = blockIdx.z * kchunk;

    f32x4 acc[2][2] = {};

    for (int ks = kBeg; ks < kBeg + kchunk; ks += 64) {
        // stage full 64x64 tile: 1024 float4-chunks = 4 passes x 256 threads
        #pragma unroll
        for (int p = 0; p < 4; p++) {
            const int c  = p * 256 + tid;      // 0..1023
            const int r  = c >> 4;             // row / k-row 0..63
            const int cq = c & 15;             // float4 chunk within 64-wide row
            float4 av = *(const float4*)&A[(size_t)(mBase + r) * lda + ks + cq * 4];
            ushort4 ao;
            ao.x = f2bf(av.x); ao.y = f2bf(av.y);
            ao.z = f2bf(av.z); ao.w = f2bf(av.w);
            *(ushort4*)&As[r * 72 + cq * 4] = ao;
            float4 bv = *(const float4*)&B[(size_t)(ks + r) * ldb + nBase + cq * 4];
            Bs[(cq * 4 + 0) * 72 + r] = f2bf(bv.x);
            Bs[(cq * 4 + 1) * 72 + r] = f2bf(bv.y);
            Bs[(cq * 4 + 2) * 72 + r] = f2bf(bv.z);
            Bs[(cq * 4 + 3) * 72 + r] = f2bf(bv.w);
        }
        __syncthreads();
        #pragma unroll
        for (int kt = 0; kt < 64; kt += 32) {
            bf16x8 af[2], bfr[2];
            #pragma unroll
            for (int mi = 0; mi < 2; mi++)
                af[mi] = *(bf16x8*)&As[(wy * 32 + mi * 16 + l16) * 72 + kt + quad * 8];
            #pragma unroll
            for (int ni = 0; ni < 2; ni++)
                bfr[ni] = *(bf16x8*)&Bs[(wx * 32 + ni * 16 + l16) * 72 + kt + quad * 8];
            #pragma unroll
            for (int mi = 0; mi < 2; mi++)
                #pragma unroll
                for (int ni = 0; ni < 2; ni++)
                    acc[mi][ni] = __builtin_amdgcn_mfma_f32_16x16x32_bf16(
                        af[mi], bfr[ni], acc[mi][ni], 0, 0, 0);
        }
        __syncthreads();
    }
    // C/D layout: col = lane&15, row = quad*4 + e  [verified m89/m91]
    #pragma unroll
    for (int mi = 0; mi < 2; mi++)
        #pragma unroll
        for (int ni = 0; ni < 2; ni++)
            #pragma unroll
            for (int e = 0; e < 4; e++) {
                const int gm = mBase + wy * 32 + mi * 16 + quad * 4 + e;
                const int gn = nBase + wx * 32 + ni * 16 + l16;
                unsafeAtomicAdd(&C[(size_t)gm * ldc + gn], acc[mi][ni][e]);
            }
}

// ---------------- per-column sum / sumsq (atomic partials) ----------------
__global__ __launch_bounds__(256) void colstats(
    const float* __restrict__ X, float* __restrict__ sum,
    float* __restrict__ sq, int rowsPerBlock)
{
    const int c = threadIdx.x;
    const int r0 = blockIdx.x * rowsPerBlock;
    float s = 0.f, q = 0.f;
    for (int r = r0; r < r0 + rowsPerBlock; ++r) {
        float v = X[r * HID + c];
        s += v;
        q = fmaf(v, v, q);
    }
    unsafeAtomicAdd(&sum[c], s);
    unsafeAtomicAdd(&sq[c], q);
}

// ---------------- BN (train-mode, biased var) + ReLU ----------------
__global__ __launch_bounds__(256) void bn_relu(
    const float* __restrict__ X, const float* __restrict__ sum,
    const float* __restrict__ sq, const float* __restrict__ g,
    const float* __restrict__ bt, float* __restrict__ Y)
{
    const int idx = blockIdx.x * 256 + threadIdx.x;
    const int cq = (idx & 63) * 4;
    float4 x = ((const float4*)X)[idx];
    float xv[4] = {x.x, x.y, x.z, x.w};
    float o[4];
    #pragma unroll
    for (int e = 0; e < 4; e++) {
        const int c = cq + e;
        float m   = sum[c] * (1.f / 1024.f);
        float var = fmaf(-m, m, sq[c] * (1.f / 1024.f));
        float rstd = rsqrtf(var + 1e-5f);
        o[e] = fmaxf(fmaf(g[c] * rstd, xv[e] - m, bt[c]), 0.f);
    }
    ((float4*)Y)[idx] = make_float4(o[0], o[1], o[2], o[3]);
}

// ---------------- fused all-pairs edge network + node update ----------------
__global__ __launch_bounds__(256) void pair_update(
    const float* __restrict__ di, const float* __restrict__ hi,
    const float* __restrict__ hj, const float* __restrict__ bwe1,
    const float* __restrict__ We2, const float* __restrict__ bwe2,
    const int* __restrict__ labels, float* __restrict__ out)
{
    __shared__ int   slab[N_PTS];
    __shared__ float sacc[4][HID];
    __shared__ float swsum[4];
    const int i = blockIdx.x;
    const int tid = threadIdx.x;
    const int lane = tid & 63;
    const int wave = tid >> 6;

    for (int t = tid; t < N_PTS; t += 256) slab[t] = labels[t];
    __syncthreads();

    const int myLab = slab[i];
    float4 hv_i = ((const float4*)(hi + (size_t)i * HID))[lane];
    float4 bw   = ((const float4*)bwe1)[lane];
    float4 w2   = ((const float4*)We2)[lane];
    const float hb0 = hv_i.x + bw.x, hb1 = hv_i.y + bw.y;
    const float hb2 = hv_i.z + bw.z, hb3 = hv_i.w + bw.w;
    const float b2 = bwe2[0];

    float a0 = 0.f, a1 = 0.f, a2 = 0.f, a3 = 0.f, wsum = 0.f;

    for (int chunk = wave * 64; chunk < N_PTS; chunk += 256) {
        const int j = chunk + lane;
        const bool match = (slab[j] == myLab) && (j != i);
        unsigned long long mask = __ballot(match);
        while (mask) {
            const int bpos = __builtin_ctzll(mask);
            mask &= mask - 1;
            const int jj = chunk + bpos;
            float4 hv = ((const float4*)(hj + (size_t)jj * HID))[lane];
            float p = fmaxf(hb0 + hv.x, 0.f) * w2.x
                    + fmaxf(hb1 + hv.y, 0.f) * w2.y
                    + fmaxf(hb2 + hv.z, 0.f) * w2.z
                    + fmaxf(hb3 + hv.w, 0.f) * w2.w;
            #pragma unroll
            for (int off = 1; off < 64; off <<= 1) p += __shfl_xor(p, off, 64);
            const float w = 1.f / (1.f + expf(-(p + b2)));
            float4 dv = ((const float4*)(di + (size_t)jj * HID))[lane];
            a0 = fmaf(w, dv.x, a0);
            a1 = fmaf(w, dv.y, a1);
            a2 = fmaf(w, dv.z, a2);
            a3 = fmaf(w, dv.w, a3);
            wsum += w;
        }
    }
    ((float4*)sacc[wave])[lane] = make_float4(a0, a1, a2, a3);
    if (lane == 0) swsum[wave] = wsum;
    __syncthreads();

    const float at = sacc[0][tid] + sacc[1][tid] + sacc[2][tid] + sacc[3][tid];
    const float wt = swsum[0] + swsum[1] + swsum[2] + swsum[3];
    const float dval = di[(size_t)i * HID + tid];
    out[(size_t)i * HID + tid] = dval + (wt > 0.f ? at / wt : 0.f);
}

extern "C" void kernel_launch(void* const* d_in, const int* in_sizes, int n_in,
                              void* d_out, int out_size, void* d_ws, size_t ws_size,
                              hipStream_t stream)
{
    const float* features = (const float*)d_in[0];
    const int*   labels   = (const int*)d_in[1];
    const float* W1   = (const float*)d_in[2];
    // b1/b2 cancel exactly through train-mode BN (mean subtraction)
    const float* g1   = (const float*)d_in[4];
    const float* bt1  = (const float*)d_in[5];
    const float* W2   = (const float*)d_in[6];
    const float* g2   = (const float*)d_in[8];
    const float* bt2  = (const float*)d_in[9];
    const float* We1  = (const float*)d_in[10];
    const float* bwe1 = (const float*)d_in[11];
    const float* We2  = (const float*)d_in[12];
    const float* bwe2 = (const float*)d_in[13];
    float* out = (float*)d_out;

    float* ws    = (float*)d_ws;
    float* x1    = ws;                 // 262144
    float* x2    = ws + 262144;        // 262144
    float* hi    = ws + 524288;        // 262144
    float* hj    = ws + 786432;        // 262144
    float* stats = ws + 1048576;       // 1024 (sum1, sq1, sum2, sq2)
    float* h     = ws + 1049600;       // 262144
    float* di    = ws + 1311744;       // 262144

    // zero atomic-accumulated buffers (x1, x2, hi, hj, stats)
    hipMemsetAsync(d_ws, 0, 1049600 * sizeof(float), stream);

    dim3 blk(256);
    // layer 1: x1 = features @ W1  [1024x2048 @ 2048x256], 8-way split-K
    gemm_mfma<<<dim3(4, 16, 8), blk, 0, stream>>>(features, W1, x1,
                                                  FEAT, HID, HID, 256);
    colstats<<<256, blk, 0, stream>>>(x1, stats, stats + 256, 4);
    bn_relu<<<256, blk, 0, stream>>>(x1, stats, stats + 256, g1, bt1, h);
    // layer 2: x2 = h @ W2  [1024x256 @ 256x256], 4-way split-K
    gemm_mfma<<<dim3(4, 16, 4), blk, 0, stream>>>(h, W2, x2,
                                                  HID, HID, HID, 64);
    colstats<<<256, blk, 0, stream>>>(x2, stats + 512, stats + 768, 4);
    bn_relu<<<256, blk, 0, stream>>>(x2, stats + 512, stats + 768, g2, bt2, di);
    // edge net halves: hi = di @ We1[:H], hj = di @ We1[H:]
    gemm_mfma<<<dim3(4, 16, 4), blk, 0, stream>>>(di, We1, hi,
                                                  HID, HID, HID, 64);
    gemm_mfma<<<dim3(4, 16, 4), blk, 0, stream>>>(di, We1 + HID * HID, hj,
                                                  HID, HID, HID, 64);
    // fused all-pairs edge weights + node feature update
    pair_update<<<N_PTS, blk, 0, stream>>>(di, hi, hj, bwe1, We2, bwe2,
                                           labels, out);
}